// Round 11
// baseline (437.234 us; speedup 1.0000x reference)
//
#include <hip/hip_runtime.h>
#include <stdint.h>

// Problem constants
#define Bdim  8
#define Edim  256
#define Kdim  64
#define Hdim  768
#define NHdim 12
#define HDdim 64
// BE = 2048

typedef __attribute__((ext_vector_type(8))) short short8;
typedef __attribute__((ext_vector_type(4))) float floatx4;
typedef unsigned short ushort_t;
typedef unsigned int u32;

#define GPLANE (2048*768)   // per-head plane stride (elements) for g and U

__device__ __forceinline__ float bf2f(ushort_t u){
  union { u32 i; float f; } v; v.i = ((u32)u) << 16; return v.f;
}
__device__ __forceinline__ ushort_t f2bf(float f){
  union { float f; u32 i; } v; v.f = f;
  u32 r = v.i + 0x7fffu + ((v.i >> 16) & 1u);   // RNE
  return (ushort_t)(r >> 16);
}
// packed 2xfp32 -> 2xbf16 (RNE), gfx950 v_cvt_pk_bf16_f32
__device__ __forceinline__ u32 cvtpk(float lo, float hi){
  u32 r;
  asm("v_cvt_pk_bf16_f32 %0, %1, %2" : "=v"(r) : "v"(lo), "v"(hi));
  return r;
}

// async global->LDS 16B (dest: wave-uniform base + lane*16)
__device__ __forceinline__ void async_ld16(void* lds, const void* g){
  __builtin_amdgcn_global_load_lds(
      (const __attribute__((address_space(1))) u32*)(uintptr_t)g,
      (__attribute__((address_space(3))) u32*)(u32)(uintptr_t)lds,
      16, 0, 0);
}

// ---------------------------------------------------------------------------
// probe_rd: contiguous grid-stride read of k_in+v_in (805 MB), reduce, write
// 2 MB to scratch (probs region; fully overwritten by attn_scores later).
// Pure measurement kernel: time = total - 263.6us baseline.
// ---------------------------------------------------------------------------
__global__ __launch_bounds__(256)
void probe_rd(const float* __restrict__ a, const float* __restrict__ b,
              float* __restrict__ o)
{
  const int gt = blockIdx.x * 256 + threadIdx.x;
  const int STRIDE = 2048 * 256;   // 524288 float4s per sweep
  const floatx4* A = (const floatx4*)a;
  const floatx4* B = (const floatx4*)b;
  float acc = 0.f;
#pragma unroll 8
  for (int i = 0; i < 48; i++){
    floatx4 v = A[(size_t)i * STRIDE + gt];
    acc += v[0] + v[1] + v[2] + v[3];
  }
#pragma unroll 8
  for (int i = 0; i < 48; i++){
    floatx4 v = B[(size_t)i * STRIDE + gt];
    acc += v[0] + v[1] + v[2] + v[3];
  }
  o[gt] = acc;
}

// ---------------------------------------------------------------------------
// GEMM (verified): C[M][768] = A[M][768](fp32) @ W^T(bf16) + bias, bf16 out
// ---------------------------------------------------------------------------
__global__ __launch_bounds__(256, 2)
void gemm_proj(const float* __restrict__ A, const ushort_t* __restrict__ W,
               const float* __restrict__ bias, ushort_t* __restrict__ Cout)
{
  __shared__ __align__(16) char smem[34816];
  const int t    = threadIdx.x;
  const int lane = t & 63;
  const int wave = t >> 6;
  const int wm   = wave >> 1, wn = wave & 1;
  const int n0   = blockIdx.x * 128;
  const int m0   = blockIdx.y * 128;

  floatx4 acc[4][4];
#pragma unroll
  for (int i = 0; i < 4; i++)
#pragma unroll
    for (int j = 0; j < 4; j++) acc[i][j] = (floatx4)0.f;

  int am[4], ac[4];
#pragma unroll
  for (int q = 0; q < 4; q++){ int idx = q*256 + t; am[q] = idx >> 3; ac[q] = idx & 7; }

  float4 areg[4];
  const int NT = Hdim / 32;

  char* const smemc = (char*)smem;
  auto Abase = [&](int b){ return smemc + b*16384; };
  auto Wbase = [&](int b){ return smemc + b*16384 + 8192; };

  auto loadA = [&](int kt){
    const float* Ap = A + (size_t)m0*768 + kt*32;
#pragma unroll
    for (int q = 0; q < 4; q++)
      areg[q] = *(const float4*)(Ap + (size_t)am[q]*768 + ac[q]*4);
  };
  auto writeA = [&](int b){
    char* base = Abase(b);
#pragma unroll
    for (int q = 0; q < 4; q++){
      u32 lo = (u32)f2bf(areg[q].x) | ((u32)f2bf(areg[q].y) << 16);
      u32 hi = (u32)f2bf(areg[q].z) | ((u32)f2bf(areg[q].w) << 16);
      int off = am[q]*64 + ((ac[q]*8) ^ ((am[q]&3) << 4));
      u32* p = (u32*)(base + off);
      p[0] = lo; p[1] = hi;
    }
  };
  auto stageW = [&](int kt, int b){
    char* base = Wbase(b);
#pragma unroll
    for (int i = 0; i < 2; i++){
      int s  = i*256 + t;
      int n  = s >> 2, kc = s & 3;
      int kcs = kc ^ (n & 3);
      const ushort_t* g = W + (size_t)(n0 + n)*768 + kt*32 + kcs*8;
      char* ldst = base + (i*256 + wave*64) * 16;
      async_ld16(ldst, g);
    }
  };
  auto compute = [&](int b){
    char* ab = Abase(b);
    char* wb = Wbase(b);
    short8 af[4], bf[4];
#pragma unroll
    for (int mi = 0; mi < 4; mi++){
      int row = wm*64 + mi*16 + (lane & 15);
      int off = row*64 + (((lane >> 4) * 16) ^ ((row & 3) << 4));
      af[mi] = *(const short8*)(ab + off);
    }
#pragma unroll
    for (int ni = 0; ni < 4; ni++){
      int row = wn*64 + ni*16 + (lane & 15);
      int off = row*64 + (((lane >> 4) * 16) ^ ((row & 3) << 4));
      bf[ni] = *(const short8*)(wb + off);
    }
#pragma unroll
    for (int mi = 0; mi < 4; mi++)
#pragma unroll
      for (int ni = 0; ni < 4; ni++)
        acc[mi][ni] = __builtin_amdgcn_mfma_f32_16x16x32_bf16(af[mi], bf[ni], acc[mi][ni], 0, 0, 0);
  };

  int buf = 0;
  loadA(0);
  stageW(0, 0);
  writeA(0);
  asm volatile("s_waitcnt vmcnt(0)" ::: "memory");
  __syncthreads();

  for (int kt = 0; kt < NT; ++kt){
    if (kt + 1 < NT){
      loadA(kt + 1);
      stageW(kt + 1, buf ^ 1);
    }
    compute(buf);
    if (kt + 1 < NT) writeA(buf ^ 1);
    asm volatile("s_waitcnt vmcnt(0)" ::: "memory");
    __syncthreads();
    buf ^= 1;
  }

  float bvv[4];
#pragma unroll
  for (int ni = 0; ni < 4; ni++) bvv[ni] = bias[n0 + wn*64 + ni*16 + (lane & 15)];

  ushort_t* sc = (ushort_t*)smem;   // [128][136] padded repack
#pragma unroll
  for (int mi = 0; mi < 4; mi++){
    int row0 = wm*64 + mi*16 + ((lane >> 4) << 2);
#pragma unroll
    for (int ni = 0; ni < 4; ni++){
      int col = wn*64 + ni*16 + (lane & 15);
#pragma unroll
      for (int r = 0; r < 4; r++)
        sc[(row0 + r)*136 + col] = f2bf(acc[mi][ni][r] + bvv[ni]);
    }
  }
  __syncthreads();
  int row = t >> 1, seg = t & 1;
  const char* src = smemc + row*272 + seg*128;
  char* dst = (char*)(Cout + (size_t)(m0 + row)*768 + n0 + seg*64);
#pragma unroll
  for (int c = 0; c < 8; c++)
    *(floatx4*)(dst + c*16) = *(const floatx4*)(src + c*16);
}

// ---------------------------------------------------------------------------
// prep: Wq cvt | Wv cvt | WkT transpose+cvt, one kernel
// ---------------------------------------------------------------------------
__global__ __launch_bounds__(256)
void prep(const float* __restrict__ Wq, const float* __restrict__ Wv,
          const float* __restrict__ Wk, ushort_t* __restrict__ Wqb,
          ushort_t* __restrict__ Wvb, ushort_t* __restrict__ WkTb)
{
  __shared__ float tile[32][33];
  const int b = blockIdx.x;
  if (b < 1152){
    const float* src = (b < 576) ? Wq : Wv;
    ushort_t*    dst = (b < 576) ? Wqb : Wvb;
    int bb = (b < 576) ? b : b - 576;
    int i = (bb * 256 + threadIdx.x) * 4;
    float4 v = *(const float4*)(src + i);
    u32* p = (u32*)(dst + i);
    p[0] = (u32)f2bf(v.x) | ((u32)f2bf(v.y) << 16);
    p[1] = (u32)f2bf(v.z) | ((u32)f2bf(v.w) << 16);
  } else {
    int bb = b - 1152;
    int bo = (bb / 24) * 32;
    int bc = (bb % 24) * 32;
    int tx = threadIdx.x & 31, ty = threadIdx.x >> 5;
#pragma unroll
    for (int i = 0; i < 4; i++)
      tile[ty + 8*i][tx] = Wk[(size_t)(bo + ty + 8*i)*768 + bc + tx];
    __syncthreads();
#pragma unroll
    for (int i = 0; i < 4; i++)
      WkTb[(size_t)(bc + ty + 8*i)*768 + bo + tx] = f2bf(tile[tx][ty + 8*i]);
  }
}

// ---------------------------------------------------------------------------
// g[h][be][c] = sum_d qp[be][h*64+d] * WkT[c][h*64+d]   (bf16, K=64)
// ---------------------------------------------------------------------------
__global__ __launch_bounds__(256)
void gemm_g(const ushort_t* __restrict__ qp, const ushort_t* __restrict__ WkT,
            ushort_t* __restrict__ g)
{
  const int h  = blockIdx.z;
  const int n0 = blockIdx.x * 128;
  const int m0 = blockIdx.y * 128;
  const int t = threadIdx.x, lane = t & 63, wave = t >> 6;
  const int wm = wave >> 1, wn = wave & 1;
  const int hl = lane & 15, jr = lane >> 4;

  floatx4 acc[4][4];
#pragma unroll
  for (int i = 0; i < 4; i++)
#pragma unroll
    for (int j = 0; j < 4; j++) acc[i][j] = (floatx4)0.f;

#pragma unroll
  for (int kt = 0; kt < 2; kt++){
    short8 af[4], bf[4];
#pragma unroll
    for (int mi = 0; mi < 4; mi++)
      af[mi] = *(const short8*)(qp + (size_t)(m0 + wm*64 + mi*16 + hl)*768 + h*64 + kt*32 + jr*8);
#pragma unroll
    for (int ni = 0; ni < 4; ni++)
      bf[ni] = *(const short8*)(WkT + (size_t)(n0 + wn*64 + ni*16 + hl)*768 + h*64 + kt*32 + jr*8);
#pragma unroll
    for (int mi = 0; mi < 4; mi++)
#pragma unroll
      for (int ni = 0; ni < 4; ni++)
        acc[mi][ni] = __builtin_amdgcn_mfma_f32_16x16x32_bf16(af[mi], bf[ni], acc[mi][ni], 0, 0, 0);
  }

  ushort_t* gp = g + (size_t)h * GPLANE;
#pragma unroll
  for (int mi = 0; mi < 4; mi++){
#pragma unroll
    for (int ni = 0; ni < 4; ni++){
      int col = n0 + wn*64 + ni*16 + hl;
#pragma unroll
      for (int r = 0; r < 4; r++){
        int row = m0 + wm*64 + mi*16 + jr*4 + r;
        gp[(size_t)row*768 + col] = f2bf(acc[mi][ni][r]);
      }
    }
  }
}

// ---------------------------------------------------------------------------
// attn_scores: scores + softmax*type -> probs[be][h][64]  (round-7 best)
// ---------------------------------------------------------------------------
__global__ __launch_bounds__(256)
void attn_scores(const float* __restrict__ k_in, const float* __restrict__ tsc,
                 const ushort_t* __restrict__ g, float* __restrict__ probs)
{
  const int be = blockIdx.x;
  const int t = threadIdx.x, lane = t & 63, w = t >> 6;
  const int hl = lane & 15, jr = lane >> 4;

  __shared__ __align__(16) ushort_t gs[12][776];   // stride 776 shorts = 1552 B
  __shared__ float redmax[4][16];
  __shared__ float redsum[4][16];

  // stage g rows for this be: 12 x 768 bf16
  {
    const ushort_t* gbase = g + (size_t)be*768;
#pragma unroll
    for (int c0 = 0; c0 < 1152; c0 += 256){
      int c = c0 + t;
      if (c < 1152){
        int row = c / 96, col = (c % 96) * 8;
        *(short8*)&gs[row][col] = *(const short8*)(gbase + (size_t)row*GPLANE + col);
      }
    }
  }
  __syncthreads();

  const float* krow = k_in + (size_t)be*Kdim*768 + (size_t)(w*16 + hl)*768;
  const int hq = (hl < 12) ? hl : 0;

  floatx4 acc = (floatx4)0.f;
  float4 f0 = *(const float4*)(krow + jr*8);
  float4 f1 = *(const float4*)(krow + jr*8 + 4);
#pragma unroll 4
  for (int kt = 0; kt < 24; kt++){
    float4 nf0, nf1;
    if (kt + 1 < 24){
      int c1 = (kt + 1)*32 + jr*8;
      nf0 = *(const float4*)(krow + c1);
      nf1 = *(const float4*)(krow + c1 + 4);
    }
    union { short8 s8; u32 wd[4]; } A;
    A.wd[0] = cvtpk(f0.x, f0.y);
    A.wd[1] = cvtpk(f0.z, f0.w);
    A.wd[2] = cvtpk(f1.x, f1.y);
    A.wd[3] = cvtpk(f1.z, f1.w);
    short8 bf = *(const short8*)&gs[hq][kt*32 + jr*8];
    acc = __builtin_amdgcn_mfma_f32_16x16x32_bf16(A.s8, bf, acc, 0, 0, 0);
    f0 = nf0; f1 = nf1;
  }

  // lane holds scores[j = w*16 + jr*4 + r][h = hl]
  float s[4];
#pragma unroll
  for (int r = 0; r < 4; r++) s[r] = acc[r] * 0.125f;

  float wmax = fmaxf(fmaxf(s[0], s[1]), fmaxf(s[2], s[3]));
  wmax = fmaxf(wmax, __shfl_xor(wmax, 16));
  wmax = fmaxf(wmax, __shfl_xor(wmax, 32));
  if (jr == 0) redmax[w][hl] = wmax;
  __syncthreads();
  float gm = fmaxf(fmaxf(redmax[0][hl], redmax[1][hl]),
                   fmaxf(redmax[2][hl], redmax[3][hl]));

  float e[4], es = 0.f;
#pragma unroll
  for (int r = 0; r < 4; r++){ e[r] = __expf(s[r] - gm); es += e[r]; }
  es += __shfl_xor(es, 16);
  es += __shfl_xor(es, 32);
  if (jr == 0) redsum[w][hl] = es;
  __syncthreads();
  float S = redsum[0][hl] + redsum[1][hl] + redsum[2][hl] + redsum[3][hl];
  float invS = 1.0f / S;

  float4 t4 = *(const float4*)(tsc + be*64 + w*16 + jr*4);
  if (hl < 12){
    float4 pv = make_float4(e[0]*invS*t4.x, e[1]*invS*t4.y,
                            e[2]*invS*t4.z, e[3]*invS*t4.w);
    *(float4*)(probs + (size_t)be*768 + hl*64 + w*16 + jr*4) = pv;
  }
}

// ---------------------------------------------------------------------------
// attn_u: u[h][c] = sum_j P[h][j] v[j][c] -> U bf16 planes; ps[h] -> ps_g
// ---------------------------------------------------------------------------
__global__ __launch_bounds__(384)
void attn_u(const float* __restrict__ v_in, const float* __restrict__ probs,
            ushort_t* __restrict__ Ug, float* __restrict__ ps_g)
{
  const int be = blockIdx.x;
  const int t = threadIdx.x;

  __shared__ float P[12][64];
  ((float*)P)[t]       = probs[(size_t)be*768 + t];
  ((float*)P)[t + 384] = probs[(size_t)be*768 + t + 384];
  __syncthreads();

  if (t < 12){
    float sum = 0.f;
#pragma unroll
    for (int jb = 0; jb < 16; jb++){
      float4 p4 = *(const float4*)&P[t][jb*4];
      sum += p4.x + p4.y + p4.z + p4.w;
    }
    ps_g[be*12 + t] = sum;
  }

  const float* vbase = v_in + (size_t)be*Kdim*768 + 2*t;
  float u0[12], u1[12];
#pragma unroll
  for (int h = 0; h < 12; h++){ u0[h] = 0.f; u1[h] = 0.f; }

  float2 v[4], nv[4];
#pragma unroll
  for (int q = 0; q < 4; q++)
    v[q] = *(const float2*)(vbase + (size_t)q*768);

#pragma unroll 2
  for (int jb = 0; jb < 16; jb++){
    if (jb + 1 < 16){
#pragma unroll
      for (int q = 0; q < 4; q++)
        nv[q] = *(const float2*)(vbase + (size_t)((jb+1)*4 + q)*768);
    }
#pragma unroll
    for (int h = 0; h < 12; h++){
      float4 p4 = *(const float4*)&P[h][jb*4];
      u0[h] += p4.x*v[0].x + p4.y*v[1].x + p4.z*v[2].x + p4.w*v[3].x;
      u1[h] += p4.x*v[0].y + p4.y*v[1].y + p4.z*v[2].y + p4.w*v[3].y;
    }
#pragma unroll
    for (int q = 0; q < 4; q++) v[q] = nv[q];
  }

#pragma unroll
  for (int h = 0; h < 12; h++)
    ((u32*)(Ug + (size_t)h*GPLANE + (size_t)be*768))[t] = cvtpk(u0[h], u1[h]);
}

// ---------------------------------------------------------------------------
// out_proj: out[be][h*64+o'] = U[h][be][:]·Wv[h*64+o'][:] + bv*ps
// ---------------------------------------------------------------------------
__global__ __launch_bounds__(256)
void out_proj(const ushort_t* __restrict__ Ug, const ushort_t* __restrict__ Wvb,
              const float* __restrict__ bv, const float* __restrict__ ps_g,
              float* __restrict__ out)
{
  const int h  = blockIdx.y;
  const int m0 = blockIdx.x * 128;
  const int t = threadIdx.x, lane = t & 63, wave = t >> 6;
  const int wm = wave >> 1, wn = wave & 1;
  const int hl = lane & 15, jr = lane >> 4;

  const ushort_t* Up = Ug + (size_t)h*GPLANE;

  floatx4 acc[4][2];
#pragma unroll
  for (int i = 0; i < 4; i++){ acc[i][0] = (floatx4)0.f; acc[i][1] = (floatx4)0.f; }

#pragma unroll 4
  for (int kt = 0; kt < 24; kt++){
    short8 af[4], bf[2];
#pragma unroll
    for (int mi = 0; mi < 4; mi++)
      af[mi] = *(const short8*)(Up + (size_t)(m0 + wm*64 + mi*16 + hl)*768 + kt*32 + jr*8);
#pragma unroll
    for (int ni = 0; ni < 2; ni++)
      bf[ni] = *(const short8*)(Wvb + (size_t)(h*64 + wn*32 + ni*16 + hl)*768 + kt*32 + jr*8);
#pragma unroll
    for (int mi = 0; mi < 4; mi++)
#pragma unroll
      for (int ni = 0; ni < 2; ni++)
        acc[mi][ni] = __builtin_amdgcn_mfma_f32_16x16x32_bf16(af[mi], bf[ni], acc[mi][ni], 0, 0, 0);
  }

  float bvo[2];
#pragma unroll
  for (int ni = 0; ni < 2; ni++) bvo[ni] = bv[h*64 + wn*32 + ni*16 + hl];

#pragma unroll
  for (int mi = 0; mi < 4; mi++){
#pragma unroll
    for (int r = 0; r < 4; r++){
      int be = m0 + wm*64 + mi*16 + jr*4 + r;
      float psv = ps_g[be*12 + h];
#pragma unroll
      for (int ni = 0; ni < 2; ni++)
        out[(size_t)be*768 + h*64 + wn*32 + ni*16 + hl] = acc[mi][ni][r] + bvo[ni]*psv;
    }
  }
}

// ---------------------------------------------------------------------------
extern "C" void kernel_launch(void* const* d_in, const int* in_sizes, int n_in,
                              void* d_out, int out_size, void* d_ws, size_t ws_size,
                              hipStream_t stream)
{
  const float* q_in = (const float*)d_in[0];
  const float* k_in = (const float*)d_in[1];
  const float* v_in = (const float*)d_in[2];
  const float* tsc  = (const float*)d_in[3];
  const float* Wq   = (const float*)d_in[4];
  const float* bq   = (const float*)d_in[5];
  const float* Wk   = (const float*)d_in[6];
  // bk dropped (softmax-invariant)
  const float* Wv   = (const float*)d_in[8];
  const float* bv   = (const float*)d_in[9];

  // ws layout (bytes):
  //   0         Wq bf16    1179648
  //   1179648   Wv bf16    1179648
  //   2359296   WkT bf16   1179648
  //   3538944   qp bf16    3145728   (2048 x 768)
  //   6684672   g bf16     37748736  (12 x 2048 x 768)
  //   44433408  U bf16     37748736  (12 x 2048 x 768)
  //   82182144  ps fp32    98304     (2048 x 12)
  //   82280448  probs f32  6291456   (2048 x 768)  -- probe scratch then probs
  // total ~84.5 MiB
  char* ws = (char*)d_ws;
  ushort_t* Wqb  = (ushort_t*)(ws);
  ushort_t* Wvb  = (ushort_t*)(ws + 1179648);
  ushort_t* WkTb = (ushort_t*)(ws + 2359296);
  ushort_t* qp   = (ushort_t*)(ws + 3538944);
  ushort_t* g    = (ushort_t*)(ws + 6684672);
  ushort_t* Ug   = (ushort_t*)(ws + 44433408);
  float*    ps_g = (float*)   (ws + 82182144);
  float*    probs= (float*)   (ws + 82280448);

  // measurement probe: contiguous read of k_in+v_in (805 MB); output scratch
  // is overwritten by attn_scores below, so results are unaffected.
  probe_rd<<<2048, 256, 0, stream>>>(k_in, v_in, probs);

  prep<<<1728, 256, 0, stream>>>(Wq, Wv, Wk, Wqb, Wvb, WkTb);

  gemm_proj<<<dim3(6, 16), 256, 0, stream>>>(q_in, Wqb, bq, qp);

  gemm_g<<<dim3(6, 16, 12), 256, 0, stream>>>(qp, WkTb, g);

  attn_scores<<<2048, 256, 0, stream>>>(k_in, tsc, g, probs);

  attn_u<<<2048, 384, 0, stream>>>(v_in, probs, Ug, ps_g);

  out_proj<<<dim3(16, 12), 256, 0, stream>>>(Ug, Wvb, bv, ps_g, (float*)d_out);
}

// Round 12
// 262.951 us; speedup vs baseline: 1.6628x; 1.6628x over previous
//
#include <hip/hip_runtime.h>
#include <stdint.h>

// Problem constants
#define Bdim  8
#define Edim  256
#define Kdim  64
#define Hdim  768
#define NHdim 12
#define HDdim 64
// BE = 2048

typedef __attribute__((ext_vector_type(8))) short short8;
typedef __attribute__((ext_vector_type(4))) float floatx4;
typedef unsigned short ushort_t;
typedef unsigned int u32;

#define GPLANE (2048*768)   // per-head plane stride (elements) for g and U

__device__ __forceinline__ float bf2f(ushort_t u){
  union { u32 i; float f; } v; v.i = ((u32)u) << 16; return v.f;
}
__device__ __forceinline__ ushort_t f2bf(float f){
  union { float f; u32 i; } v; v.f = f;
  u32 r = v.i + 0x7fffu + ((v.i >> 16) & 1u);   // RNE
  return (ushort_t)(r >> 16);
}
// packed 2xfp32 -> 2xbf16 (RNE), gfx950 v_cvt_pk_bf16_f32
__device__ __forceinline__ u32 cvtpk(float lo, float hi){
  u32 r;
  asm("v_cvt_pk_bf16_f32 %0, %1, %2" : "=v"(r) : "v"(lo), "v"(hi));
  return r;
}

// async global->LDS 16B (dest: wave-uniform base + lane*16)
__device__ __forceinline__ void async_ld16(void* lds, const void* g){
  __builtin_amdgcn_global_load_lds(
      (const __attribute__((address_space(1))) u32*)(uintptr_t)g,
      (__attribute__((address_space(3))) u32*)(u32)(uintptr_t)lds,
      16, 0, 0);
}

// ---------------------------------------------------------------------------
// GEMM (verified): C[M][768] = A[M][768](fp32) @ W^T(bf16) + bias, bf16 out
// ---------------------------------------------------------------------------
__global__ __launch_bounds__(256, 2)
void gemm_proj(const float* __restrict__ A, const ushort_t* __restrict__ W,
               const float* __restrict__ bias, ushort_t* __restrict__ Cout)
{
  __shared__ __align__(16) char smem[34816];
  const int t    = threadIdx.x;
  const int lane = t & 63;
  const int wave = t >> 6;
  const int wm   = wave >> 1, wn = wave & 1;
  const int n0   = blockIdx.x * 128;
  const int m0   = blockIdx.y * 128;

  floatx4 acc[4][4];
#pragma unroll
  for (int i = 0; i < 4; i++)
#pragma unroll
    for (int j = 0; j < 4; j++) acc[i][j] = (floatx4)0.f;

  int am[4], ac[4];
#pragma unroll
  for (int q = 0; q < 4; q++){ int idx = q*256 + t; am[q] = idx >> 3; ac[q] = idx & 7; }

  float4 areg[4];
  const int NT = Hdim / 32;

  char* const smemc = (char*)smem;
  auto Abase = [&](int b){ return smemc + b*16384; };
  auto Wbase = [&](int b){ return smemc + b*16384 + 8192; };

  auto loadA = [&](int kt){
    const float* Ap = A + (size_t)m0*768 + kt*32;
#pragma unroll
    for (int q = 0; q < 4; q++)
      areg[q] = *(const float4*)(Ap + (size_t)am[q]*768 + ac[q]*4);
  };
  auto writeA = [&](int b){
    char* base = Abase(b);
#pragma unroll
    for (int q = 0; q < 4; q++){
      u32 lo = (u32)f2bf(areg[q].x) | ((u32)f2bf(areg[q].y) << 16);
      u32 hi = (u32)f2bf(areg[q].z) | ((u32)f2bf(areg[q].w) << 16);
      int off = am[q]*64 + ((ac[q]*8) ^ ((am[q]&3) << 4));
      u32* p = (u32*)(base + off);
      p[0] = lo; p[1] = hi;
    }
  };
  auto stageW = [&](int kt, int b){
    char* base = Wbase(b);
#pragma unroll
    for (int i = 0; i < 2; i++){
      int s  = i*256 + t;
      int n  = s >> 2, kc = s & 3;
      int kcs = kc ^ (n & 3);
      const ushort_t* g = W + (size_t)(n0 + n)*768 + kt*32 + kcs*8;
      char* ldst = base + (i*256 + wave*64) * 16;
      async_ld16(ldst, g);
    }
  };
  auto compute = [&](int b){
    char* ab = Abase(b);
    char* wb = Wbase(b);
    short8 af[4], bf[4];
#pragma unroll
    for (int mi = 0; mi < 4; mi++){
      int row = wm*64 + mi*16 + (lane & 15);
      int off = row*64 + (((lane >> 4) * 16) ^ ((row & 3) << 4));
      af[mi] = *(const short8*)(ab + off);
    }
#pragma unroll
    for (int ni = 0; ni < 4; ni++){
      int row = wn*64 + ni*16 + (lane & 15);
      int off = row*64 + (((lane >> 4) * 16) ^ ((row & 3) << 4));
      bf[ni] = *(const short8*)(wb + off);
    }
#pragma unroll
    for (int mi = 0; mi < 4; mi++)
#pragma unroll
      for (int ni = 0; ni < 4; ni++)
        acc[mi][ni] = __builtin_amdgcn_mfma_f32_16x16x32_bf16(af[mi], bf[ni], acc[mi][ni], 0, 0, 0);
  };

  int buf = 0;
  loadA(0);
  stageW(0, 0);
  writeA(0);
  asm volatile("s_waitcnt vmcnt(0)" ::: "memory");
  __syncthreads();

  for (int kt = 0; kt < NT; ++kt){
    if (kt + 1 < NT){
      loadA(kt + 1);
      stageW(kt + 1, buf ^ 1);
    }
    compute(buf);
    if (kt + 1 < NT) writeA(buf ^ 1);
    asm volatile("s_waitcnt vmcnt(0)" ::: "memory");
    __syncthreads();
    buf ^= 1;
  }

  float bvv[4];
#pragma unroll
  for (int ni = 0; ni < 4; ni++) bvv[ni] = bias[n0 + wn*64 + ni*16 + (lane & 15)];

  ushort_t* sc = (ushort_t*)smem;   // [128][136] padded repack
#pragma unroll
  for (int mi = 0; mi < 4; mi++){
    int row0 = wm*64 + mi*16 + ((lane >> 4) << 2);
#pragma unroll
    for (int ni = 0; ni < 4; ni++){
      int col = wn*64 + ni*16 + (lane & 15);
#pragma unroll
      for (int r = 0; r < 4; r++)
        sc[(row0 + r)*136 + col] = f2bf(acc[mi][ni][r] + bvv[ni]);
    }
  }
  __syncthreads();
  int row = t >> 1, seg = t & 1;
  const char* src = smemc + row*272 + seg*128;
  char* dst = (char*)(Cout + (size_t)(m0 + row)*768 + n0 + seg*64);
#pragma unroll
  for (int c = 0; c < 8; c++)
    *(floatx4*)(dst + c*16) = *(const floatx4*)(src + c*16);
}

// ---------------------------------------------------------------------------
// prep: Wq cvt | Wv cvt | WkT transpose+cvt, one kernel
// ---------------------------------------------------------------------------
__global__ __launch_bounds__(256)
void prep(const float* __restrict__ Wq, const float* __restrict__ Wv,
          const float* __restrict__ Wk, ushort_t* __restrict__ Wqb,
          ushort_t* __restrict__ Wvb, ushort_t* __restrict__ WkTb)
{
  __shared__ float tile[32][33];
  const int b = blockIdx.x;
  if (b < 1152){
    const float* src = (b < 576) ? Wq : Wv;
    ushort_t*    dst = (b < 576) ? Wqb : Wvb;
    int bb = (b < 576) ? b : b - 576;
    int i = (bb * 256 + threadIdx.x) * 4;
    float4 v = *(const float4*)(src + i);
    u32* p = (u32*)(dst + i);
    p[0] = (u32)f2bf(v.x) | ((u32)f2bf(v.y) << 16);
    p[1] = (u32)f2bf(v.z) | ((u32)f2bf(v.w) << 16);
  } else {
    int bb = b - 1152;
    int bo = (bb / 24) * 32;
    int bc = (bb % 24) * 32;
    int tx = threadIdx.x & 31, ty = threadIdx.x >> 5;
#pragma unroll
    for (int i = 0; i < 4; i++)
      tile[ty + 8*i][tx] = Wk[(size_t)(bo + ty + 8*i)*768 + bc + tx];
    __syncthreads();
#pragma unroll
    for (int i = 0; i < 4; i++)
      WkTb[(size_t)(bc + ty + 8*i)*768 + bo + tx] = f2bf(tile[tx][ty + 8*i]);
  }
}

// ---------------------------------------------------------------------------
// g[h][be][c] = sum_d qp[be][h*64+d] * WkT[c][h*64+d]   (bf16, K=64)
// ---------------------------------------------------------------------------
__global__ __launch_bounds__(256)
void gemm_g(const ushort_t* __restrict__ qp, const ushort_t* __restrict__ WkT,
            ushort_t* __restrict__ g)
{
  const int h  = blockIdx.z;
  const int n0 = blockIdx.x * 128;
  const int m0 = blockIdx.y * 128;
  const int t = threadIdx.x, lane = t & 63, wave = t >> 6;
  const int wm = wave >> 1, wn = wave & 1;
  const int hl = lane & 15, jr = lane >> 4;

  floatx4 acc[4][4];
#pragma unroll
  for (int i = 0; i < 4; i++)
#pragma unroll
    for (int j = 0; j < 4; j++) acc[i][j] = (floatx4)0.f;

#pragma unroll
  for (int kt = 0; kt < 2; kt++){
    short8 af[4], bf[4];
#pragma unroll
    for (int mi = 0; mi < 4; mi++)
      af[mi] = *(const short8*)(qp + (size_t)(m0 + wm*64 + mi*16 + hl)*768 + h*64 + kt*32 + jr*8);
#pragma unroll
    for (int ni = 0; ni < 4; ni++)
      bf[ni] = *(const short8*)(WkT + (size_t)(n0 + wn*64 + ni*16 + hl)*768 + h*64 + kt*32 + jr*8);
#pragma unroll
    for (int mi = 0; mi < 4; mi++)
#pragma unroll
      for (int ni = 0; ni < 4; ni++)
        acc[mi][ni] = __builtin_amdgcn_mfma_f32_16x16x32_bf16(af[mi], bf[ni], acc[mi][ni], 0, 0, 0);
  }

  ushort_t* gp = g + (size_t)h * GPLANE;
#pragma unroll
  for (int mi = 0; mi < 4; mi++){
#pragma unroll
    for (int ni = 0; ni < 4; ni++){
      int col = n0 + wn*64 + ni*16 + hl;
#pragma unroll
      for (int r = 0; r < 4; r++){
        int row = m0 + wm*64 + mi*16 + jr*4 + r;
        gp[(size_t)row*768 + col] = f2bf(acc[mi][ni][r]);
      }
    }
  }
}

// ---------------------------------------------------------------------------
// attn_scores: scores + softmax*type -> probs[be][h][64]  (round-7 best)
// ---------------------------------------------------------------------------
__global__ __launch_bounds__(256)
void attn_scores(const float* __restrict__ k_in, const float* __restrict__ tsc,
                 const ushort_t* __restrict__ g, float* __restrict__ probs)
{
  const int be = blockIdx.x;
  const int t = threadIdx.x, lane = t & 63, w = t >> 6;
  const int hl = lane & 15, jr = lane >> 4;

  __shared__ __align__(16) ushort_t gs[12][776];   // stride 776 shorts = 1552 B
  __shared__ float redmax[4][16];
  __shared__ float redsum[4][16];

  // stage g rows for this be: 12 x 768 bf16
  {
    const ushort_t* gbase = g + (size_t)be*768;
#pragma unroll
    for (int c0 = 0; c0 < 1152; c0 += 256){
      int c = c0 + t;
      if (c < 1152){
        int row = c / 96, col = (c % 96) * 8;
        *(short8*)&gs[row][col] = *(const short8*)(gbase + (size_t)row*GPLANE + col);
      }
    }
  }
  __syncthreads();

  const float* krow = k_in + (size_t)be*Kdim*768 + (size_t)(w*16 + hl)*768;
  const int hq = (hl < 12) ? hl : 0;

  floatx4 acc = (floatx4)0.f;
  float4 f0 = *(const float4*)(krow + jr*8);
  float4 f1 = *(const float4*)(krow + jr*8 + 4);
#pragma unroll 4
  for (int kt = 0; kt < 24; kt++){
    float4 nf0, nf1;
    if (kt + 1 < 24){
      int c1 = (kt + 1)*32 + jr*8;
      nf0 = *(const float4*)(krow + c1);
      nf1 = *(const float4*)(krow + c1 + 4);
    }
    union { short8 s8; u32 wd[4]; } A;
    A.wd[0] = cvtpk(f0.x, f0.y);
    A.wd[1] = cvtpk(f0.z, f0.w);
    A.wd[2] = cvtpk(f1.x, f1.y);
    A.wd[3] = cvtpk(f1.z, f1.w);
    short8 bf = *(const short8*)&gs[hq][kt*32 + jr*8];
    acc = __builtin_amdgcn_mfma_f32_16x16x32_bf16(A.s8, bf, acc, 0, 0, 0);
    f0 = nf0; f1 = nf1;
  }

  // lane holds scores[j = w*16 + jr*4 + r][h = hl]
  float s[4];
#pragma unroll
  for (int r = 0; r < 4; r++) s[r] = acc[r] * 0.125f;

  float wmax = fmaxf(fmaxf(s[0], s[1]), fmaxf(s[2], s[3]));
  wmax = fmaxf(wmax, __shfl_xor(wmax, 16));
  wmax = fmaxf(wmax, __shfl_xor(wmax, 32));
  if (jr == 0) redmax[w][hl] = wmax;
  __syncthreads();
  float gm = fmaxf(fmaxf(redmax[0][hl], redmax[1][hl]),
                   fmaxf(redmax[2][hl], redmax[3][hl]));

  float e[4], es = 0.f;
#pragma unroll
  for (int r = 0; r < 4; r++){ e[r] = __expf(s[r] - gm); es += e[r]; }
  es += __shfl_xor(es, 16);
  es += __shfl_xor(es, 32);
  if (jr == 0) redsum[w][hl] = es;
  __syncthreads();
  float S = redsum[0][hl] + redsum[1][hl] + redsum[2][hl] + redsum[3][hl];
  float invS = 1.0f / S;

  float4 t4 = *(const float4*)(tsc + be*64 + w*16 + jr*4);
  if (hl < 12){
    float4 pv = make_float4(e[0]*invS*t4.x, e[1]*invS*t4.y,
                            e[2]*invS*t4.z, e[3]*invS*t4.w);
    *(float4*)(probs + (size_t)be*768 + hl*64 + w*16 + jr*4) = pv;
  }
}

// ---------------------------------------------------------------------------
// attn_u: u[h][c] = sum_j P[h][j] v[j][c] -> U bf16 planes; ps[h] -> ps_g
// ---------------------------------------------------------------------------
__global__ __launch_bounds__(384)
void attn_u(const float* __restrict__ v_in, const float* __restrict__ probs,
            ushort_t* __restrict__ Ug, float* __restrict__ ps_g)
{
  const int be = blockIdx.x;
  const int t = threadIdx.x;

  __shared__ float P[12][64];
  ((float*)P)[t]       = probs[(size_t)be*768 + t];
  ((float*)P)[t + 384] = probs[(size_t)be*768 + t + 384];
  __syncthreads();

  if (t < 12){
    float sum = 0.f;
#pragma unroll
    for (int jb = 0; jb < 16; jb++){
      float4 p4 = *(const float4*)&P[t][jb*4];
      sum += p4.x + p4.y + p4.z + p4.w;
    }
    ps_g[be*12 + t] = sum;
  }

  const float* vbase = v_in + (size_t)be*Kdim*768 + 2*t;
  float u0[12], u1[12];
#pragma unroll
  for (int h = 0; h < 12; h++){ u0[h] = 0.f; u1[h] = 0.f; }

  float2 v[4], nv[4];
#pragma unroll
  for (int q = 0; q < 4; q++)
    v[q] = *(const float2*)(vbase + (size_t)q*768);

#pragma unroll 2
  for (int jb = 0; jb < 16; jb++){
    if (jb + 1 < 16){
#pragma unroll
      for (int q = 0; q < 4; q++)
        nv[q] = *(const float2*)(vbase + (size_t)((jb+1)*4 + q)*768);
    }
#pragma unroll
    for (int h = 0; h < 12; h++){
      float4 p4 = *(const float4*)&P[h][jb*4];
      u0[h] += p4.x*v[0].x + p4.y*v[1].x + p4.z*v[2].x + p4.w*v[3].x;
      u1[h] += p4.x*v[0].y + p4.y*v[1].y + p4.z*v[2].y + p4.w*v[3].y;
    }
#pragma unroll
    for (int q = 0; q < 4; q++) v[q] = nv[q];
  }

#pragma unroll
  for (int h = 0; h < 12; h++)
    ((u32*)(Ug + (size_t)h*GPLANE + (size_t)be*768))[t] = cvtpk(u0[h], u1[h]);
}

// ---------------------------------------------------------------------------
// out_proj: out[be][h*64+o'] = U[h][be][:]·Wv[h*64+o'][:] + bv*ps
// ---------------------------------------------------------------------------
__global__ __launch_bounds__(256)
void out_proj(const ushort_t* __restrict__ Ug, const ushort_t* __restrict__ Wvb,
              const float* __restrict__ bv, const float* __restrict__ ps_g,
              float* __restrict__ out)
{
  const int h  = blockIdx.y;
  const int m0 = blockIdx.x * 128;
  const int t = threadIdx.x, lane = t & 63, wave = t >> 6;
  const int wm = wave >> 1, wn = wave & 1;
  const int hl = lane & 15, jr = lane >> 4;

  const ushort_t* Up = Ug + (size_t)h*GPLANE;

  floatx4 acc[4][2];
#pragma unroll
  for (int i = 0; i < 4; i++){ acc[i][0] = (floatx4)0.f; acc[i][1] = (floatx4)0.f; }

#pragma unroll 4
  for (int kt = 0; kt < 24; kt++){
    short8 af[4], bf[2];
#pragma unroll
    for (int mi = 0; mi < 4; mi++)
      af[mi] = *(const short8*)(Up + (size_t)(m0 + wm*64 + mi*16 + hl)*768 + kt*32 + jr*8);
#pragma unroll
    for (int ni = 0; ni < 2; ni++)
      bf[ni] = *(const short8*)(Wvb + (size_t)(h*64 + wn*32 + ni*16 + hl)*768 + kt*32 + jr*8);
#pragma unroll
    for (int mi = 0; mi < 4; mi++)
#pragma unroll
      for (int ni = 0; ni < 2; ni++)
        acc[mi][ni] = __builtin_amdgcn_mfma_f32_16x16x32_bf16(af[mi], bf[ni], acc[mi][ni], 0, 0, 0);
  }

  float bvo[2];
#pragma unroll
  for (int ni = 0; ni < 2; ni++) bvo[ni] = bv[h*64 + wn*32 + ni*16 + hl];

#pragma unroll
  for (int mi = 0; mi < 4; mi++){
#pragma unroll
    for (int r = 0; r < 4; r++){
      int be = m0 + wm*64 + mi*16 + jr*4 + r;
      float psv = ps_g[be*12 + h];
#pragma unroll
      for (int ni = 0; ni < 2; ni++)
        out[(size_t)be*768 + h*64 + wn*32 + ni*16 + hl] = acc[mi][ni][r] + bvo[ni]*psv;
    }
  }
}

// ---------------------------------------------------------------------------
extern "C" void kernel_launch(void* const* d_in, const int* in_sizes, int n_in,
                              void* d_out, int out_size, void* d_ws, size_t ws_size,
                              hipStream_t stream)
{
  const float* q_in = (const float*)d_in[0];
  const float* k_in = (const float*)d_in[1];
  const float* v_in = (const float*)d_in[2];
  const float* tsc  = (const float*)d_in[3];
  const float* Wq   = (const float*)d_in[4];
  const float* bq   = (const float*)d_in[5];
  const float* Wk   = (const float*)d_in[6];
  // bk dropped (softmax-invariant)
  const float* Wv   = (const float*)d_in[8];
  const float* bv   = (const float*)d_in[9];

  // ws layout (bytes):
  //   0         Wq bf16    1179648
  //   1179648   Wv bf16    1179648
  //   2359296   WkT bf16   1179648
  //   3538944   qp bf16    3145728   (2048 x 768)
  //   6684672   g bf16     37748736  (12 x 2048 x 768)
  //   44433408  U bf16     37748736  (12 x 2048 x 768)
  //   82182144  ps fp32    98304     (2048 x 12)
  //   82280448  probs f32  6291456   (2048 x 768)
  // total ~84.5 MiB
  char* ws = (char*)d_ws;
  ushort_t* Wqb  = (ushort_t*)(ws);
  ushort_t* Wvb  = (ushort_t*)(ws + 1179648);
  ushort_t* WkTb = (ushort_t*)(ws + 2359296);
  ushort_t* qp   = (ushort_t*)(ws + 3538944);
  ushort_t* g    = (ushort_t*)(ws + 6684672);
  ushort_t* Ug   = (ushort_t*)(ws + 44433408);
  float*    ps_g = (float*)   (ws + 82182144);
  float*    probs= (float*)   (ws + 82280448);

  prep<<<1728, 256, 0, stream>>>(Wq, Wv, Wk, Wqb, Wvb, WkTb);

  gemm_proj<<<dim3(6, 16), 256, 0, stream>>>(q_in, Wqb, bq, qp);

  gemm_g<<<dim3(6, 16, 12), 256, 0, stream>>>(qp, WkTb, g);

  attn_scores<<<2048, 256, 0, stream>>>(k_in, tsc, g, probs);

  attn_u<<<2048, 384, 0, stream>>>(v_in, probs, Ug, ps_g);

  out_proj<<<dim3(16, 12), 256, 0, stream>>>(Ug, Wvb, bv, ps_g, (float*)d_out);
}